// Round 3
// baseline (247.982 us; speedup 1.0000x reference)
//
#include <hip/hip_runtime.h>
#include <math.h>

// Problem constants (from setup_inputs)
#define NN 100000            // nodes
#define NE 1600000           // real edges
#define ET (NE + NN)         // edges + self loops = 1,700,000
#define FIN 128
#define H1 4
#define C1 8
#define F1 32                // H1*C1
#define FOUT 16
#define NSLOPE 0.2f

// Radix-partition parameters (CSR build)
#define PARTW 256                          // nodes per dst-partition
#define PSHIFT 8
#define NPART ((NN + PARTW - 1) / PARTW)   // 391
#define CHUNK 8192                         // edges per hist/part block
#define NBLK ((ET + CHUNK - 1) / CHUNK)    // 208
#define CPAD 16                            // ints: 1 global counter per 64B line
#define SMASK 0x1FFFF                      // low 17 bits = src id

typedef _Float16 half8 __attribute__((ext_vector_type(8)));
typedef _Float16 half4_t __attribute__((ext_vector_type(4)));
typedef _Float16 half2_t __attribute__((ext_vector_type(2)));
typedef float f32x4 __attribute__((ext_vector_type(4)));

// fp8 e4m3 (OCP on gfx950) decode: byte SEL of packed word -> f32.
// SEL must be an immediate for the builtin -> template non-type parameter.
template <int SEL>
__device__ inline float fp8dec(unsigned int w) {
    return __builtin_amdgcn_cvt_f32_fp8((int)w, SEL);
}

// ---------------- scan helpers ----------------

__device__ inline int wave_incl_scan(int v) {
#pragma unroll
    for (int off = 1; off < 64; off <<= 1) {
        int u = __shfl_up(v, off);
        if ((threadIdx.x & 63) >= off) v += u;
    }
    return v;
}

__device__ inline int block_excl_scan(int v, int* wsum, int nw) {
    int t = threadIdx.x, wid = t >> 6, lane = t & 63;
    int incl = wave_incl_scan(v);
    if (lane == 63) wsum[wid] = incl;
    __syncthreads();
    if (wid == 0) {
        int wv = (lane < nw) ? wsum[lane] : 0;
        wv = wave_incl_scan(wv);
        if (lane < nw) wsum[lane] = wv;
    }
    __syncthreads();
    return incl - v + (wid ? wsum[wid - 1] : 0);
}

// ---------------- CSR build (R10 versions) ----------------

__global__ __launch_bounds__(1024) void k_hist(const int* __restrict__ dstA, int* __restrict__ ptotal) {
    __shared__ int h[NPART];
    int t = threadIdx.x;
    for (int i = t; i < NPART; i += 1024) h[i] = 0;
    __syncthreads();
    int base = blockIdx.x * CHUNK;
#pragma unroll
    for (int k = 0; k < CHUNK / 1024; k++) {
        int e = base + k * 1024 + t;
        if (e < ET) {
            int d = (e < NE) ? dstA[e] : (e - NE);   // virtual self-loop edges
            atomicAdd(&h[d >> PSHIFT], 1);
        }
    }
    __syncthreads();
    for (int i = t; i < NPART; i += 1024)
        if (h[i]) atomicAdd(&ptotal[i * CPAD], h[i]);
}

__global__ __launch_bounds__(512) void k_pbase(const int* __restrict__ ptotal, int* __restrict__ pbase,
                                               int* __restrict__ gcur, int* __restrict__ rowstart) {
    __shared__ int wsum[8];
    int t = threadIdx.x;
    int v = (t < NPART) ? ptotal[t * CPAD] : 0;
    int excl = block_excl_scan(v, wsum, 8);
    if (t < NPART) { pbase[t] = excl; gcur[t * CPAD] = excl; }
    if (t == 0) { pbase[NPART] = ET; rowstart[NN] = ET; }
}

__global__ __launch_bounds__(1024) void k_part(const int* __restrict__ srcA, const int* __restrict__ dstA,
                                               int* __restrict__ gcur, int* __restrict__ pairs) {
    __shared__ int h[NPART];
    __shared__ int cur[NPART];
    int t = threadIdx.x;
    for (int i = t; i < NPART; i += 1024) h[i] = 0;
    __syncthreads();
    int base = blockIdx.x * CHUNK;
#pragma unroll
    for (int k = 0; k < CHUNK / 1024; k++) {
        int e = base + k * 1024 + t;
        if (e < ET) {
            int d = (e < NE) ? dstA[e] : (e - NE);
            atomicAdd(&h[d >> PSHIFT], 1);
        }
    }
    __syncthreads();
    for (int i = t; i < NPART; i += 1024) {
        int c = h[i];
        cur[i] = c ? atomicAdd(&gcur[i * CPAD], c) : 0;   // reserve contiguous range
    }
    __syncthreads();
#pragma unroll
    for (int k = 0; k < CHUNK / 1024; k++) {
        int e = base + k * 1024 + t;
        if (e < ET) {
            int s, d;
            if (e < NE) { s = srcA[e]; d = dstA[e]; }
            else        { s = e - NE;  d = s; }
            int pos = atomicAdd(&cur[d >> PSHIFT], 1);    // LDS atomic
            pairs[pos] = ((d & (PARTW - 1)) << 17) | s;   // src < 2^17, dloc < 2^8
        }
    }
}

__global__ __launch_bounds__(1024) void k_sort(const int* __restrict__ pbase, const int* __restrict__ pairs,
                                               int* __restrict__ rowstart, int* __restrict__ epack) {
    __shared__ int hist[PARTW];
    __shared__ int sa[PARTW], sb[PARTW];
    int p = blockIdx.x;
    int t = threadIdx.x;
    int n0 = p << PSHIFT;
    int nn = min(PARTW, NN - n0);
    int base = pbase[p];
    int cnt = pbase[p + 1] - base;
    if (t < PARTW) hist[t] = 0;
    __syncthreads();
    for (int i = t; i < cnt; i += 1024)
        atomicAdd(&hist[pairs[base + i] >> 17], 1);
    __syncthreads();
    if (t < PARTW) sa[t] = hist[t];
    __syncthreads();
    int* pin = sa; int* pout = sb;
    for (int off = 1; off < PARTW; off <<= 1) {
        if (t < PARTW) pout[t] = pin[t] + ((t >= off) ? pin[t - off] : 0);
        __syncthreads();
        int* tmp = pin; pin = pout; pout = tmp;
    }
    int excl = 0;
    if (t < PARTW) {
        excl = pin[t] - hist[t];
        if (t < nn) rowstart[n0 + t] = base + excl;
    }
    __syncthreads();
    if (t < PARTW) hist[t] = excl;   // reuse as cursor
    __syncthreads();
    for (int i = t; i < cnt; i += 1024) {
        int v = pairs[base + i];
        int pos = base + atomicAdd(&hist[v >> 17], 1);  // LDS atomic
        epack[pos] = v;
    }
}

// ---------------- Layer 1: x@W1 via MFMA ----------------
// Output xw1 stored as fp8 e4m3 (row = 32 ch = 8 u32 = 32B): halves the random
// gather footprint in k_gather1 AND makes the table (3.2MB) per-XCD-L2 resident.

__global__ __launch_bounds__(256) void k_gemm1(const float* __restrict__ x, const float* __restrict__ W1,
        const float* __restrict__ a1s, const float* __restrict__ a1d,
        unsigned int* __restrict__ xw1b, float* __restrict__ as1, float* __restrict__ ad1) {
    __shared__ _Float16 w1t[F1 * FIN];   // [n][k], 8 KB
    __shared__ float xs[256 * F1];       // [node_loc][col], 32 KB
    int t = threadIdx.x;
    {
        int i0 = t * 16;
#pragma unroll
        for (int i = 0; i < 16; i++) {
            int idx = i0 + i;
            int k = idx >> 5, n = idx & 31;
            w1t[n * FIN + k] = (_Float16)W1[idx];
        }
    }
    __syncthreads();
    int w = t >> 6, l = t & 63;
    int q = l >> 4, r16 = l & 15;
    int nblk = blockIdx.x * 256;
    int n0 = nblk + w * 64;
    half8 bf[4][2];
#pragma unroll
    for (int kc = 0; kc < 4; kc++)
#pragma unroll
        for (int nt = 0; nt < 2; nt++)
            bf[kc][nt] = *(const half8*)&w1t[(nt * 16 + r16) * FIN + kc * 32 + q * 8];
#pragma unroll
    for (int mt = 0; mt < 4; mt++) {
        int row = n0 + mt * 16 + r16;
        int rowc = min(row, NN - 1);            // clamp: values discarded for OOB rows
        const float4* xp = (const float4*)(x + (size_t)rowc * FIN + q * 8);
        half8 af[4];
#pragma unroll
        for (int kc = 0; kc < 4; kc++) {
            float4 u = xp[kc * 8];
            float4 v = xp[kc * 8 + 1];
            half8 a;
            a[0] = (_Float16)u.x; a[1] = (_Float16)u.y; a[2] = (_Float16)u.z; a[3] = (_Float16)u.w;
            a[4] = (_Float16)v.x; a[5] = (_Float16)v.y; a[6] = (_Float16)v.z; a[7] = (_Float16)v.w;
            af[kc] = a;
        }
        f32x4 acc0 = {0.f, 0.f, 0.f, 0.f};
        f32x4 acc1 = {0.f, 0.f, 0.f, 0.f};
#pragma unroll
        for (int kc = 0; kc < 4; kc++) {
            acc0 = __builtin_amdgcn_mfma_f32_16x16x32_f16(af[kc], bf[kc][0], acc0, 0, 0, 0);
            acc1 = __builtin_amdgcn_mfma_f32_16x16x32_f16(af[kc], bf[kc][1], acc1, 0, 0, 0);
        }
#pragma unroll
        for (int r = 0; r < 4; r++) {
            xs[(w * 64 + mt * 16 + q * 4 + r) * F1 + r16] = acc0[r];
            xs[(w * 64 + mt * 16 + q * 4 + r) * F1 + 16 + r16] = acc1[r];
        }
    }
    int node = nblk + w * 64 + l;
    if (node < NN) {
        const float4* xr = (const float4*)&xs[(w * 64 + l) * F1];
        float rowv[F1];
#pragma unroll
        for (int j = 0; j < 8; j++) {
            float4 v = xr[j];
            rowv[j * 4] = v.x; rowv[j * 4 + 1] = v.y; rowv[j * 4 + 2] = v.z; rowv[j * 4 + 3] = v.w;
        }
        // pack 32 channels -> 8 u32 of fp8 e4m3
        uint4 o[2];
        unsigned int* ow = (unsigned int*)o;
#pragma unroll
        for (int c4 = 0; c4 < 8; c4++) {
            int p = 0;
            p = __builtin_amdgcn_cvt_pk_fp8_f32(rowv[c4 * 4 + 0], rowv[c4 * 4 + 1], p, false);
            p = __builtin_amdgcn_cvt_pk_fp8_f32(rowv[c4 * 4 + 2], rowv[c4 * 4 + 3], p, true);
            ow[c4] = (unsigned int)p;
        }
        uint4* o16 = (uint4*)(xw1b + (size_t)node * 8);
        o16[0] = o[0];
        o16[1] = o[1];
        float ss[H1], dd[H1];
#pragma unroll
        for (int h = 0; h < H1; h++) {
            ss[h] = 0.f; dd[h] = 0.f;
#pragma unroll
            for (int c = 0; c < C1; c++) {
                ss[h] = fmaf(rowv[h * C1 + c], a1s[h * C1 + c], ss[h]);
                dd[h] = fmaf(rowv[h * C1 + c], a1d[h * C1 + c], dd[h]);
            }
        }
        ((float4*)as1)[node] = make_float4(ss[0], ss[1], ss[2], ss[3]);
        ((float4*)ad1)[node] = make_float4(dd[0], dd[1], dd[2], dd[3]);
    }
}

// ---------------- Layer 1 gather: fp8 rows, 8 lanes/edge, 3-stage pipeline ----------------
// 1 wave/node. 8 edge-groups x 8 lanes; lane j owns channels {4j..4j+3} via one
// u32 (4 fp8) load; head j>>1 unique per lane -> 1 as1 read + 1 exp per lane per
// edge. Row = 32B random fetch from a 3.2MB table (L2-resident per XCD).

__global__ __launch_bounds__(256) void k_gather1(const int* __restrict__ rowstart, const int* __restrict__ epack,
        const float* __restrict__ as1, const float* __restrict__ ad1,
        const unsigned int* __restrict__ xw1b, const float* __restrict__ b1,
        _Float16* __restrict__ h1h) {
    int n = blockIdx.x * 4 + (threadIdx.x >> 6);
    if (n >= NN) return;
    int l = threadIdx.x & 63;
    int g = l >> 3;          // edge group 0..7
    int j = l & 7;           // channel-quad id 0..7
    int h = j >> 1;          // head 0..3
    float adh = ad1[n * H1 + h];
    int beg = rowstart[n], end = rowstart[n + 1];
    int endm1 = end - 1;
    float a0 = 0.f, a1 = 0.f, a2 = 0.f, a3 = 0.f, ad = 0.f;
    int i = beg + g;
    // stage 0+1: current pair (f/v ready), next pair's src ids
    int i0 = min(i, endm1), i1 = min(i + 8, endm1);
    int c0 = epack[i0] & SMASK, c1 = epack[i1] & SMASK;
    int i2 = min(i + 16, endm1), i3 = min(i + 24, endm1);
    int sn0 = epack[i2] & SMASK, sn1 = epack[i3] & SMASK;
    float f0 = as1[c0 * H1 + h], f1 = as1[c1 * H1 + h];
    unsigned int v0 = xw1b[c0 * 8 + j], v1 = xw1b[c1 * 8 + j];
    while (i + 8 < end) {
        // issue dependent loads for i+16 (ids already resident)
        float nf0 = as1[sn0 * H1 + h], nf1 = as1[sn1 * H1 + h];
        unsigned int nv0 = xw1b[sn0 * 8 + j], nv1 = xw1b[sn1 * 8 + j];
        // issue epack loads for i+32
        int p0 = min(i + 32, endm1), p1 = min(i + 40, endm1);
        int u0 = epack[p0] & SMASK, u1 = epack[p1] & SMASK;
        // consume current pair
        float e0 = f0 + adh, e1 = f1 + adh;
        e0 = (e0 > 0.f) ? e0 : NSLOPE * e0;
        e1 = (e1 > 0.f) ? e1 : NSLOPE * e1;
        float w0 = __expf(e0), w1 = __expf(e1);
        ad += w0 + w1;
        a0 = fmaf(w0, fp8dec<0>(v0), fmaf(w1, fp8dec<0>(v1), a0));
        a1 = fmaf(w0, fp8dec<1>(v0), fmaf(w1, fp8dec<1>(v1), a1));
        a2 = fmaf(w0, fp8dec<2>(v0), fmaf(w1, fp8dec<2>(v1), a2));
        a3 = fmaf(w0, fp8dec<3>(v0), fmaf(w1, fp8dec<3>(v1), a3));
        f0 = nf0; f1 = nf1; v0 = nv0; v1 = nv1;
        sn0 = u0; sn1 = u1;
        i += 16;
    }
    if (i < end) {           // at most one leftover edge per lane (i+8 >= end)
        float e0 = f0 + adh;
        e0 = (e0 > 0.f) ? e0 : NSLOPE * e0;
        float w0 = __expf(e0);
        ad += w0;
        a0 = fmaf(w0, fp8dec<0>(v0), a0);
        a1 = fmaf(w0, fp8dec<1>(v0), a1);
        a2 = fmaf(w0, fp8dec<2>(v0), a2);
        a3 = fmaf(w0, fp8dec<3>(v0), a3);
    }
#pragma unroll
    for (int off = 8; off < 64; off <<= 1) {
        a0 += __shfl_xor(a0, off);
        a1 += __shfl_xor(a1, off);
        a2 += __shfl_xor(a2, off);
        a3 += __shfl_xor(a3, off);
        ad += __shfl_xor(ad, off);
    }
    if (l < 8) {
        float inv = 1.0f / ad;
        float y0 = fmaf(a0, inv, b1[4 * j]);
        float y1 = fmaf(a1, inv, b1[4 * j + 1]);
        float y2 = fmaf(a2, inv, b1[4 * j + 2]);
        float y3 = fmaf(a3, inv, b1[4 * j + 3]);
        y0 = (y0 > 0.f) ? y0 : expm1f(y0);   // ELU
        y1 = (y1 > 0.f) ? y1 : expm1f(y1);
        y2 = (y2 > 0.f) ? y2 : expm1f(y2);
        y3 = (y3 > 0.f) ? y3 : expm1f(y3);
        half4_t o;
        o[0] = (_Float16)y0; o[1] = (_Float16)y1; o[2] = (_Float16)y2; o[3] = (_Float16)y3;
        ((half4_t*)h1h)[(size_t)n * 8 + j] = o;
    }
}

// ---------------- Layer 2 node transform: h1@W2 + attention coefficients ----------------

__global__ __launch_bounds__(256) void k_node2(const _Float16* __restrict__ h1h, const float* __restrict__ W2,
        const float* __restrict__ a2s, const float* __restrict__ a2d,
        _Float16* __restrict__ xw2h, float* __restrict__ as2, float* __restrict__ ad2) {
    int n = blockIdx.x * 256 + threadIdx.x;
    if (n >= NN) return;
    float acc[FOUT];
#pragma unroll
    for (int j = 0; j < FOUT; j++) acc[j] = 0.f;
    const half8* h8 = (const half8*)(h1h + (size_t)n * F1);
#pragma unroll
    for (int i8 = 0; i8 < F1 / 8; i8++) {
        half8 hv = h8[i8];
#pragma unroll
        for (int kk = 0; kk < 8; kk++) {
            float hk = (float)hv[kk];
            int i = i8 * 8 + kk;
#pragma unroll
            for (int j = 0; j < FOUT; j++)
                acc[j] = fmaf(hk, W2[i * FOUT + j], acc[j]);   // wave-uniform -> scalar
        }
    }
    float ss = 0.f, dd = 0.f;
#pragma unroll
    for (int j = 0; j < FOUT; j++) {
        ss = fmaf(acc[j], a2s[j], ss);
        dd = fmaf(acc[j], a2d[j], dd);
    }
    half8* o8 = (half8*)(xw2h + (size_t)n * FOUT);
#pragma unroll
    for (int j8 = 0; j8 < FOUT / 8; j8++) {
        half8 o;
#pragma unroll
        for (int k = 0; k < 8; k++) o[k] = (_Float16)acc[j8 * 8 + k];
        o8[j8] = o;
    }
    as2[n] = ss;
    ad2[n] = dd;
}

// ---------------- Layer 2 gather: 3-stage pipeline + log_softmax ----------------
// 1 wave/node. 8 edge-groups x 8 lanes; lane j owns channels {2j,2j+1}; single
// head -> 1 as2 read + 1 exp per lane. Same pipeline skeleton as k_gather1.

__global__ __launch_bounds__(256) void k_gather2(const int* __restrict__ rowstart, const int* __restrict__ epack,
        const float* __restrict__ as2, const float* __restrict__ ad2,
        const _Float16* __restrict__ xw2h, const float* __restrict__ b2,
        float* __restrict__ out) {
    int n = blockIdx.x * 4 + (threadIdx.x >> 6);
    if (n >= NN) return;
    int l = threadIdx.x & 63;
    int g = l >> 3;          // edge group 0..7
    int j = l & 7;           // channel-pair id 0..7
    float adn = ad2[n];
    const half2_t* xw = (const half2_t*)xw2h;   // row = 8 half2
    int beg = rowstart[n], end = rowstart[n + 1];
    int endm1 = end - 1;
    float a0 = 0.f, a1v = 0.f, ad = 0.f;
    int i = beg + g;
    int i0 = min(i, endm1), i1 = min(i + 8, endm1);
    int c0 = epack[i0] & SMASK, c1 = epack[i1] & SMASK;
    int i2 = min(i + 16, endm1), i3 = min(i + 24, endm1);
    int sn0 = epack[i2] & SMASK, sn1 = epack[i3] & SMASK;
    float f0 = as2[c0], f1 = as2[c1];
    half2_t v0 = xw[c0 * 8 + j], v1 = xw[c1 * 8 + j];
    while (i + 8 < end) {
        float nf0 = as2[sn0], nf1 = as2[sn1];
        half2_t nv0 = xw[sn0 * 8 + j], nv1 = xw[sn1 * 8 + j];
        int p0 = min(i + 32, endm1), p1 = min(i + 40, endm1);
        int u0 = epack[p0] & SMASK, u1 = epack[p1] & SMASK;
        float e0 = f0 + adn, e1 = f1 + adn;
        e0 = (e0 > 0.f) ? e0 : NSLOPE * e0;
        e1 = (e1 > 0.f) ? e1 : NSLOPE * e1;
        float w0 = __expf(e0), w1 = __expf(e1);
        ad += w0 + w1;
        a0  = fmaf(w0, (float)v0[0], fmaf(w1, (float)v1[0], a0));
        a1v = fmaf(w0, (float)v0[1], fmaf(w1, (float)v1[1], a1v));
        f0 = nf0; f1 = nf1; v0 = nv0; v1 = nv1;
        sn0 = u0; sn1 = u1;
        i += 16;
    }
    if (i < end) {
        float e0 = f0 + adn;
        e0 = (e0 > 0.f) ? e0 : NSLOPE * e0;
        float w0 = __expf(e0);
        ad += w0;
        a0  = fmaf(w0, (float)v0[0], a0);
        a1v = fmaf(w0, (float)v0[1], a1v);
    }
#pragma unroll
    for (int off = 8; off < 64; off <<= 1) {
        a0  += __shfl_xor(a0, off);
        a1v += __shfl_xor(a1v, off);
        ad  += __shfl_xor(ad, off);
    }
    float inv = 1.0f / ad;
    float y0 = fmaf(a0, inv, b2[2 * j]);
    float y1 = fmaf(a1v, inv, b2[2 * j + 1]);
    // log_softmax over 16 channels (8 lanes x 2 regs)
    float m = fmaxf(y0, y1);
#pragma unroll
    for (int off = 1; off < 8; off <<= 1) m = fmaxf(m, __shfl_xor(m, off));
    float s = __expf(y0 - m) + __expf(y1 - m);
#pragma unroll
    for (int off = 1; off < 8; off <<= 1) s += __shfl_xor(s, off);
    float ls = logf(s);
    if (l < 8)
        ((float2*)out)[(size_t)n * 8 + j] = make_float2(y0 - m - ls, y1 - m - ls);
}

// ---------------- launch ----------------

extern "C" void kernel_launch(void* const* d_in, const int* in_sizes, int n_in,
                              void* d_out, int out_size, void* d_ws, size_t ws_size,
                              hipStream_t stream) {
    const float* x   = (const float*)d_in[0];
    const int*   ei  = (const int*)d_in[1];
    const float* W1  = (const float*)d_in[2];
    const float* a1s = (const float*)d_in[3];
    const float* a1d = (const float*)d_in[4];
    const float* b1  = (const float*)d_in[5];
    const float* W2  = (const float*)d_in[6];
    const float* a2s = (const float*)d_in[7];
    const float* a2d = (const float*)d_in[8];
    const float* b2  = (const float*)d_in[9];
    float* out = (float*)d_out;

    const int* srcA = ei;        // edge_index[0]
    const int* dstA = ei + NE;   // edge_index[1]

    char* w = (char*)d_ws;
    size_t off = 0;
    auto carve = [&](size_t bytes) -> void* {
        void* p = w + off;
        off = (off + bytes + 255) & ~(size_t)255;
        return p;
    };
    unsigned int* xw1b = (unsigned int*)carve((size_t)NN * 32); // 3.2 MB fp8 rows
    float* as1     = (float*)carve((size_t)NN * H1 * 4);      // 1.6 MB
    float* ad1     = (float*)carve((size_t)NN * H1 * 4);      // 1.6 MB
    // pairs (6.8MB) aliases h1h+xw2h (9.6MB): pairs dies at k_sort, h1h/xw2h
    // are written only by later kernels (stream-ordered) -> safe.
    size_t h1_off  = off;
    _Float16* h1h  = (_Float16*)carve((size_t)NN * F1 * 2);   // 6.4 MB
    _Float16* xw2h = (_Float16*)carve((size_t)NN * FOUT * 2); // 3.2 MB
    float* as2     = (float*)carve((size_t)NN * 4);
    float* ad2     = (float*)carve((size_t)NN * 4);
    int* pairs     = (int*)(w + h1_off);                      // alias
    int* rowstart  = (int*)carve((size_t)(NN + 1) * 4);
    int* epack     = (int*)carve((size_t)(ET + 64) * 4);      // 6.8 MB (+pad)
    int* ptotal    = (int*)carve((size_t)NPART * CPAD * 4);   // 25 KB
    int* gcur      = (int*)carve((size_t)NPART * CPAD * 4);   // 25 KB
    int* pbase     = (int*)carve((size_t)(NPART + 1) * 4);
    (void)ws_size; (void)in_sizes; (void)n_in; (void)out_size;

    hipMemsetAsync(ptotal, 0, (size_t)NPART * CPAD * 4, stream);

    k_hist  <<<NBLK, 1024, 0, stream>>>(dstA, ptotal);
    k_pbase <<<1, 512, 0, stream>>>(ptotal, pbase, gcur, rowstart);
    k_part  <<<NBLK, 1024, 0, stream>>>(srcA, dstA, gcur, pairs);
    k_sort  <<<NPART, 1024, 0, stream>>>(pbase, pairs, rowstart, epack);

    k_gemm1 <<<(NN + 255) / 256, 256, 0, stream>>>(x, W1, a1s, a1d, xw1b, as1, ad1);
    k_gather1<<<(NN + 3) / 4, 256, 0, stream>>>(rowstart, epack, as1, ad1, xw1b, b1, h1h);
    k_node2 <<<(NN + 255) / 256, 256, 0, stream>>>(h1h, W2, a2s, a2d, xw2h, as2, ad2);
    k_gather2<<<(NN + 3) / 4, 256, 0, stream>>>(rowstart, epack, as2, ad2, xw2h, b2, out);
}

// Round 4
// 245.695 us; speedup vs baseline: 1.0093x; 1.0093x over previous
//
#include <hip/hip_runtime.h>
#include <math.h>

// Problem constants (from setup_inputs)
#define NN 100000            // nodes
#define NE 1600000           // real edges
#define ET (NE + NN)         // edges + self loops = 1,700,000
#define FIN 128
#define H1 4
#define C1 8
#define F1 32                // H1*C1
#define FOUT 16
#define NSLOPE 0.2f

// Radix-partition parameters (CSR build)
#define PARTW 256                          // nodes per dst-partition
#define PSHIFT 8
#define NPART ((NN + PARTW - 1) / PARTW)   // 391
#define CHUNK 8192                         // edges per hist/part block
#define NBLK ((ET + CHUNK - 1) / CHUNK)    // 208
#define CPAD 16                            // ints: 1 global counter per 64B line
#define SMASK 0x1FFFF                      // low 17 bits = src id

// Gather kernels: multi-node-per-wave (latency amortization)
#define KNODES 13
#define GBLK 2048                          // 2048 blocks x 4 waves = 8192 waves

typedef _Float16 half8 __attribute__((ext_vector_type(8)));
typedef _Float16 half4_t __attribute__((ext_vector_type(4)));
typedef _Float16 half2_t __attribute__((ext_vector_type(2)));
typedef float f32x4 __attribute__((ext_vector_type(4)));

// fp8 e4m3 (OCP on gfx950) decode: byte SEL of packed word -> f32.
// SEL must be an immediate for the builtin -> template non-type parameter.
template <int SEL>
__device__ inline float fp8dec(unsigned int w) {
    return __builtin_amdgcn_cvt_f32_fp8((int)w, SEL);
}

// ---------------- scan helpers ----------------

__device__ inline int wave_incl_scan(int v) {
#pragma unroll
    for (int off = 1; off < 64; off <<= 1) {
        int u = __shfl_up(v, off);
        if ((threadIdx.x & 63) >= off) v += u;
    }
    return v;
}

__device__ inline int block_excl_scan(int v, int* wsum, int nw) {
    int t = threadIdx.x, wid = t >> 6, lane = t & 63;
    int incl = wave_incl_scan(v);
    if (lane == 63) wsum[wid] = incl;
    __syncthreads();
    if (wid == 0) {
        int wv = (lane < nw) ? wsum[lane] : 0;
        wv = wave_incl_scan(wv);
        if (lane < nw) wsum[lane] = wv;
    }
    __syncthreads();
    return incl - v + (wid ? wsum[wid - 1] : 0);
}

// ---------------- CSR build (R10 versions) ----------------

__global__ __launch_bounds__(1024) void k_hist(const int* __restrict__ dstA, int* __restrict__ ptotal) {
    __shared__ int h[NPART];
    int t = threadIdx.x;
    for (int i = t; i < NPART; i += 1024) h[i] = 0;
    __syncthreads();
    int base = blockIdx.x * CHUNK;
#pragma unroll
    for (int k = 0; k < CHUNK / 1024; k++) {
        int e = base + k * 1024 + t;
        if (e < ET) {
            int d = (e < NE) ? dstA[e] : (e - NE);   // virtual self-loop edges
            atomicAdd(&h[d >> PSHIFT], 1);
        }
    }
    __syncthreads();
    for (int i = t; i < NPART; i += 1024)
        if (h[i]) atomicAdd(&ptotal[i * CPAD], h[i]);
}

__global__ __launch_bounds__(512) void k_pbase(const int* __restrict__ ptotal, int* __restrict__ pbase,
                                               int* __restrict__ gcur, int* __restrict__ rowstart) {
    __shared__ int wsum[8];
    int t = threadIdx.x;
    int v = (t < NPART) ? ptotal[t * CPAD] : 0;
    int excl = block_excl_scan(v, wsum, 8);
    if (t < NPART) { pbase[t] = excl; gcur[t * CPAD] = excl; }
    if (t == 0) { pbase[NPART] = ET; rowstart[NN] = ET; }
}

__global__ __launch_bounds__(1024) void k_part(const int* __restrict__ srcA, const int* __restrict__ dstA,
                                               int* __restrict__ gcur, int* __restrict__ pairs) {
    __shared__ int h[NPART];
    __shared__ int cur[NPART];
    int t = threadIdx.x;
    for (int i = t; i < NPART; i += 1024) h[i] = 0;
    __syncthreads();
    int base = blockIdx.x * CHUNK;
#pragma unroll
    for (int k = 0; k < CHUNK / 1024; k++) {
        int e = base + k * 1024 + t;
        if (e < ET) {
            int d = (e < NE) ? dstA[e] : (e - NE);
            atomicAdd(&h[d >> PSHIFT], 1);
        }
    }
    __syncthreads();
    for (int i = t; i < NPART; i += 1024) {
        int c = h[i];
        cur[i] = c ? atomicAdd(&gcur[i * CPAD], c) : 0;   // reserve contiguous range
    }
    __syncthreads();
#pragma unroll
    for (int k = 0; k < CHUNK / 1024; k++) {
        int e = base + k * 1024 + t;
        if (e < ET) {
            int s, d;
            if (e < NE) { s = srcA[e]; d = dstA[e]; }
            else        { s = e - NE;  d = s; }
            int pos = atomicAdd(&cur[d >> PSHIFT], 1);    // LDS atomic
            pairs[pos] = ((d & (PARTW - 1)) << 17) | s;   // src < 2^17, dloc < 2^8
        }
    }
}

__global__ __launch_bounds__(1024) void k_sort(const int* __restrict__ pbase, const int* __restrict__ pairs,
                                               int* __restrict__ rowstart, int* __restrict__ epack) {
    __shared__ int hist[PARTW];
    __shared__ int sa[PARTW], sb[PARTW];
    int p = blockIdx.x;
    int t = threadIdx.x;
    int n0 = p << PSHIFT;
    int nn = min(PARTW, NN - n0);
    int base = pbase[p];
    int cnt = pbase[p + 1] - base;
    if (t < PARTW) hist[t] = 0;
    __syncthreads();
    for (int i = t; i < cnt; i += 1024)
        atomicAdd(&hist[pairs[base + i] >> 17], 1);
    __syncthreads();
    if (t < PARTW) sa[t] = hist[t];
    __syncthreads();
    int* pin = sa; int* pout = sb;
    for (int off = 1; off < PARTW; off <<= 1) {
        if (t < PARTW) pout[t] = pin[t] + ((t >= off) ? pin[t - off] : 0);
        __syncthreads();
        int* tmp = pin; pin = pout; pout = tmp;
    }
    int excl = 0;
    if (t < PARTW) {
        excl = pin[t] - hist[t];
        if (t < nn) rowstart[n0 + t] = base + excl;
    }
    __syncthreads();
    if (t < PARTW) hist[t] = excl;   // reuse as cursor
    __syncthreads();
    for (int i = t; i < cnt; i += 1024) {
        int v = pairs[base + i];
        int pos = base + atomicAdd(&hist[v >> 17], 1);  // LDS atomic
        epack[pos] = v;
    }
}

// ---------------- Layer 1: x@W1 via MFMA ----------------
// Output xw1 stored as fp8 e4m3 (row = 32 ch = 8 u32 = 32B): halves the random
// gather footprint in k_gather1 AND makes the table (3.2MB) per-XCD-L2 resident.

__global__ __launch_bounds__(256) void k_gemm1(const float* __restrict__ x, const float* __restrict__ W1,
        const float* __restrict__ a1s, const float* __restrict__ a1d,
        unsigned int* __restrict__ xw1b, float* __restrict__ as1, float* __restrict__ ad1) {
    __shared__ _Float16 w1t[F1 * FIN];   // [n][k], 8 KB
    __shared__ float xs[256 * F1];       // [node_loc][col], 32 KB
    int t = threadIdx.x;
    {
        int i0 = t * 16;
#pragma unroll
        for (int i = 0; i < 16; i++) {
            int idx = i0 + i;
            int k = idx >> 5, n = idx & 31;
            w1t[n * FIN + k] = (_Float16)W1[idx];
        }
    }
    __syncthreads();
    int w = t >> 6, l = t & 63;
    int q = l >> 4, r16 = l & 15;
    int nblk = blockIdx.x * 256;
    int n0 = nblk + w * 64;
    half8 bf[4][2];
#pragma unroll
    for (int kc = 0; kc < 4; kc++)
#pragma unroll
        for (int nt = 0; nt < 2; nt++)
            bf[kc][nt] = *(const half8*)&w1t[(nt * 16 + r16) * FIN + kc * 32 + q * 8];
#pragma unroll
    for (int mt = 0; mt < 4; mt++) {
        int row = n0 + mt * 16 + r16;
        int rowc = min(row, NN - 1);            // clamp: values discarded for OOB rows
        const float4* xp = (const float4*)(x + (size_t)rowc * FIN + q * 8);
        half8 af[4];
#pragma unroll
        for (int kc = 0; kc < 4; kc++) {
            float4 u = xp[kc * 8];
            float4 v = xp[kc * 8 + 1];
            half8 a;
            a[0] = (_Float16)u.x; a[1] = (_Float16)u.y; a[2] = (_Float16)u.z; a[3] = (_Float16)u.w;
            a[4] = (_Float16)v.x; a[5] = (_Float16)v.y; a[6] = (_Float16)v.z; a[7] = (_Float16)v.w;
            af[kc] = a;
        }
        f32x4 acc0 = {0.f, 0.f, 0.f, 0.f};
        f32x4 acc1 = {0.f, 0.f, 0.f, 0.f};
#pragma unroll
        for (int kc = 0; kc < 4; kc++) {
            acc0 = __builtin_amdgcn_mfma_f32_16x16x32_f16(af[kc], bf[kc][0], acc0, 0, 0, 0);
            acc1 = __builtin_amdgcn_mfma_f32_16x16x32_f16(af[kc], bf[kc][1], acc1, 0, 0, 0);
        }
#pragma unroll
        for (int r = 0; r < 4; r++) {
            xs[(w * 64 + mt * 16 + q * 4 + r) * F1 + r16] = acc0[r];
            xs[(w * 64 + mt * 16 + q * 4 + r) * F1 + 16 + r16] = acc1[r];
        }
    }
    int node = nblk + w * 64 + l;
    if (node < NN) {
        const float4* xr = (const float4*)&xs[(w * 64 + l) * F1];
        float rowv[F1];
#pragma unroll
        for (int j = 0; j < 8; j++) {
            float4 v = xr[j];
            rowv[j * 4] = v.x; rowv[j * 4 + 1] = v.y; rowv[j * 4 + 2] = v.z; rowv[j * 4 + 3] = v.w;
        }
        // pack 32 channels -> 8 u32 of fp8 e4m3
        uint4 o[2];
        unsigned int* ow = (unsigned int*)o;
#pragma unroll
        for (int c4 = 0; c4 < 8; c4++) {
            int p = 0;
            p = __builtin_amdgcn_cvt_pk_fp8_f32(rowv[c4 * 4 + 0], rowv[c4 * 4 + 1], p, false);
            p = __builtin_amdgcn_cvt_pk_fp8_f32(rowv[c4 * 4 + 2], rowv[c4 * 4 + 3], p, true);
            ow[c4] = (unsigned int)p;
        }
        uint4* o16 = (uint4*)(xw1b + (size_t)node * 8);
        o16[0] = o[0];
        o16[1] = o[1];
        float ss[H1], dd[H1];
#pragma unroll
        for (int h = 0; h < H1; h++) {
            ss[h] = 0.f; dd[h] = 0.f;
#pragma unroll
            for (int c = 0; c < C1; c++) {
                ss[h] = fmaf(rowv[h * C1 + c], a1s[h * C1 + c], ss[h]);
                dd[h] = fmaf(rowv[h * C1 + c], a1d[h * C1 + c], dd[h]);
            }
        }
        ((float4*)as1)[node] = make_float4(ss[0], ss[1], ss[2], ss[3]);
        ((float4*)ad1)[node] = make_float4(dd[0], dd[1], dd[2], dd[3]);
    }
}

// ---------------- Layer 1 gather: multi-node waves, fp8 rows, 3-stage pipeline ----------------
// 8192 waves total; each wave serially processes KNODES consecutive nodes.
// Amortizes the per-wave dependent-load chain (rowstart->epack->as1/xw->reduce)
// that R1/R3 showed dominates (lifetime ~6600cy for ~17 edges of work).
// rowstart for the whole range is loaded ONCE per wave (lane-parallel + shfl).
// Per node: 8 edge-groups x 8 lanes; lane j owns channels {4j..4j+3} via one
// u32 (4 fp8) load; head j>>1 unique per lane.

__global__ __launch_bounds__(256) void k_gather1(const int* __restrict__ rowstart, const int* __restrict__ epack,
        const float* __restrict__ as1, const float* __restrict__ ad1,
        const unsigned int* __restrict__ xw1b, const float* __restrict__ b1,
        _Float16* __restrict__ h1h) {
    int wid = blockIdx.x * 4 + (threadIdx.x >> 6);
    int nbeg = wid * KNODES;
    if (nbeg >= NN) return;
    int ncnt = min(KNODES, NN - nbeg);
    int l = threadIdx.x & 63;
    int g = l >> 3;          // edge group 0..7
    int j = l & 7;           // channel-quad id 0..7
    int h = j >> 1;          // head 0..3
    float bj0 = b1[4 * j], bj1 = b1[4 * j + 1], bj2 = b1[4 * j + 2], bj3 = b1[4 * j + 3];
    int rs = rowstart[nbeg + min(l, ncnt)];   // lanes 0..ncnt hold the range bounds
    for (int k = 0; k < ncnt; k++) {
        int beg = __shfl(rs, k);
        int end = __shfl(rs, k + 1);
        int n = nbeg + k;
        float adh = ad1[n * H1 + h];
        int endm1 = end - 1;
        float a0 = 0.f, a1 = 0.f, a2 = 0.f, a3 = 0.f, ad = 0.f;
        int i = beg + g;
        // stage 0+1: current pair (f/v ready), next pair's src ids
        int i0 = min(i, endm1), i1 = min(i + 8, endm1);
        int c0 = epack[i0] & SMASK, c1 = epack[i1] & SMASK;
        int i2 = min(i + 16, endm1), i3 = min(i + 24, endm1);
        int sn0 = epack[i2] & SMASK, sn1 = epack[i3] & SMASK;
        float f0 = as1[c0 * H1 + h], f1 = as1[c1 * H1 + h];
        unsigned int v0 = xw1b[c0 * 8 + j], v1 = xw1b[c1 * 8 + j];
        while (i + 8 < end) {
            // issue dependent loads for i+16 (ids already resident)
            float nf0 = as1[sn0 * H1 + h], nf1 = as1[sn1 * H1 + h];
            unsigned int nv0 = xw1b[sn0 * 8 + j], nv1 = xw1b[sn1 * 8 + j];
            // issue epack loads for i+32
            int p0 = min(i + 32, endm1), p1 = min(i + 40, endm1);
            int u0 = epack[p0] & SMASK, u1 = epack[p1] & SMASK;
            // consume current pair
            float e0 = f0 + adh, e1 = f1 + adh;
            e0 = (e0 > 0.f) ? e0 : NSLOPE * e0;
            e1 = (e1 > 0.f) ? e1 : NSLOPE * e1;
            float w0 = __expf(e0), w1 = __expf(e1);
            ad += w0 + w1;
            a0 = fmaf(w0, fp8dec<0>(v0), fmaf(w1, fp8dec<0>(v1), a0));
            a1 = fmaf(w0, fp8dec<1>(v0), fmaf(w1, fp8dec<1>(v1), a1));
            a2 = fmaf(w0, fp8dec<2>(v0), fmaf(w1, fp8dec<2>(v1), a2));
            a3 = fmaf(w0, fp8dec<3>(v0), fmaf(w1, fp8dec<3>(v1), a3));
            f0 = nf0; f1 = nf1; v0 = nv0; v1 = nv1;
            sn0 = u0; sn1 = u1;
            i += 16;
        }
        if (i < end) {       // at most one leftover edge per lane (i+8 >= end)
            float e0 = f0 + adh;
            e0 = (e0 > 0.f) ? e0 : NSLOPE * e0;
            float w0 = __expf(e0);
            ad += w0;
            a0 = fmaf(w0, fp8dec<0>(v0), a0);
            a1 = fmaf(w0, fp8dec<1>(v0), a1);
            a2 = fmaf(w0, fp8dec<2>(v0), a2);
            a3 = fmaf(w0, fp8dec<3>(v0), a3);
        }
#pragma unroll
        for (int off = 8; off < 64; off <<= 1) {
            a0 += __shfl_xor(a0, off);
            a1 += __shfl_xor(a1, off);
            a2 += __shfl_xor(a2, off);
            a3 += __shfl_xor(a3, off);
            ad += __shfl_xor(ad, off);
        }
        if (l < 8) {
            float inv = 1.0f / ad;
            float y0 = fmaf(a0, inv, bj0);
            float y1 = fmaf(a1, inv, bj1);
            float y2 = fmaf(a2, inv, bj2);
            float y3 = fmaf(a3, inv, bj3);
            y0 = (y0 > 0.f) ? y0 : expm1f(y0);   // ELU
            y1 = (y1 > 0.f) ? y1 : expm1f(y1);
            y2 = (y2 > 0.f) ? y2 : expm1f(y2);
            y3 = (y3 > 0.f) ? y3 : expm1f(y3);
            half4_t o;
            o[0] = (_Float16)y0; o[1] = (_Float16)y1; o[2] = (_Float16)y2; o[3] = (_Float16)y3;
            ((half4_t*)h1h)[(size_t)n * 8 + j] = o;
        }
    }
}

// ---------------- Layer 2 node transform: h1@W2 + attention coefficients ----------------

__global__ __launch_bounds__(256) void k_node2(const _Float16* __restrict__ h1h, const float* __restrict__ W2,
        const float* __restrict__ a2s, const float* __restrict__ a2d,
        _Float16* __restrict__ xw2h, float* __restrict__ as2, float* __restrict__ ad2) {
    int n = blockIdx.x * 256 + threadIdx.x;
    if (n >= NN) return;
    float acc[FOUT];
#pragma unroll
    for (int j = 0; j < FOUT; j++) acc[j] = 0.f;
    const half8* h8 = (const half8*)(h1h + (size_t)n * F1);
#pragma unroll
    for (int i8 = 0; i8 < F1 / 8; i8++) {
        half8 hv = h8[i8];
#pragma unroll
        for (int kk = 0; kk < 8; kk++) {
            float hk = (float)hv[kk];
            int i = i8 * 8 + kk;
#pragma unroll
            for (int j = 0; j < FOUT; j++)
                acc[j] = fmaf(hk, W2[i * FOUT + j], acc[j]);   // wave-uniform -> scalar
        }
    }
    float ss = 0.f, dd = 0.f;
#pragma unroll
    for (int j = 0; j < FOUT; j++) {
        ss = fmaf(acc[j], a2s[j], ss);
        dd = fmaf(acc[j], a2d[j], dd);
    }
    half8* o8 = (half8*)(xw2h + (size_t)n * FOUT);
#pragma unroll
    for (int j8 = 0; j8 < FOUT / 8; j8++) {
        half8 o;
#pragma unroll
        for (int k = 0; k < 8; k++) o[k] = (_Float16)acc[j8 * 8 + k];
        o8[j8] = o;
    }
    as2[n] = ss;
    ad2[n] = dd;
}

// ---------------- Layer 2 gather: multi-node waves + log_softmax ----------------
// Same multi-node restructure as k_gather1. 8 edge-groups x 8 lanes; lane j
// owns channels {2j,2j+1}; single head -> 1 as2 read + 1 exp per lane.

__global__ __launch_bounds__(256) void k_gather2(const int* __restrict__ rowstart, const int* __restrict__ epack,
        const float* __restrict__ as2, const float* __restrict__ ad2,
        const _Float16* __restrict__ xw2h, const float* __restrict__ b2,
        float* __restrict__ out) {
    int wid = blockIdx.x * 4 + (threadIdx.x >> 6);
    int nbeg = wid * KNODES;
    if (nbeg >= NN) return;
    int ncnt = min(KNODES, NN - nbeg);
    int l = threadIdx.x & 63;
    int g = l >> 3;          // edge group 0..7
    int j = l & 7;           // channel-pair id 0..7
    float bj0 = b2[2 * j], bj1 = b2[2 * j + 1];
    const half2_t* xw = (const half2_t*)xw2h;   // row = 8 half2
    int rs = rowstart[nbeg + min(l, ncnt)];
    for (int k = 0; k < ncnt; k++) {
        int beg = __shfl(rs, k);
        int end = __shfl(rs, k + 1);
        int n = nbeg + k;
        float adn = ad2[n];
        int endm1 = end - 1;
        float a0 = 0.f, a1v = 0.f, ad = 0.f;
        int i = beg + g;
        int i0 = min(i, endm1), i1 = min(i + 8, endm1);
        int c0 = epack[i0] & SMASK, c1 = epack[i1] & SMASK;
        int i2 = min(i + 16, endm1), i3 = min(i + 24, endm1);
        int sn0 = epack[i2] & SMASK, sn1 = epack[i3] & SMASK;
        float f0 = as2[c0], f1 = as2[c1];
        half2_t v0 = xw[c0 * 8 + j], v1 = xw[c1 * 8 + j];
        while (i + 8 < end) {
            float nf0 = as2[sn0], nf1 = as2[sn1];
            half2_t nv0 = xw[sn0 * 8 + j], nv1 = xw[sn1 * 8 + j];
            int p0 = min(i + 32, endm1), p1 = min(i + 40, endm1);
            int u0 = epack[p0] & SMASK, u1 = epack[p1] & SMASK;
            float e0 = f0 + adn, e1 = f1 + adn;
            e0 = (e0 > 0.f) ? e0 : NSLOPE * e0;
            e1 = (e1 > 0.f) ? e1 : NSLOPE * e1;
            float w0 = __expf(e0), w1 = __expf(e1);
            ad += w0 + w1;
            a0  = fmaf(w0, (float)v0[0], fmaf(w1, (float)v1[0], a0));
            a1v = fmaf(w0, (float)v0[1], fmaf(w1, (float)v1[1], a1v));
            f0 = nf0; f1 = nf1; v0 = nv0; v1 = nv1;
            sn0 = u0; sn1 = u1;
            i += 16;
        }
        if (i < end) {
            float e0 = f0 + adn;
            e0 = (e0 > 0.f) ? e0 : NSLOPE * e0;
            float w0 = __expf(e0);
            ad += w0;
            a0  = fmaf(w0, (float)v0[0], a0);
            a1v = fmaf(w0, (float)v0[1], a1v);
        }
#pragma unroll
        for (int off = 8; off < 64; off <<= 1) {
            a0  += __shfl_xor(a0, off);
            a1v += __shfl_xor(a1v, off);
            ad  += __shfl_xor(ad, off);
        }
        float inv = 1.0f / ad;
        float y0 = fmaf(a0, inv, bj0);
        float y1 = fmaf(a1v, inv, bj1);
        // log_softmax over 16 channels (8 lanes x 2 regs)
        float m = fmaxf(y0, y1);
#pragma unroll
        for (int off = 1; off < 8; off <<= 1) m = fmaxf(m, __shfl_xor(m, off));
        float s = __expf(y0 - m) + __expf(y1 - m);
#pragma unroll
        for (int off = 1; off < 8; off <<= 1) s += __shfl_xor(s, off);
        float ls = logf(s);
        if (l < 8)
            ((float2*)out)[(size_t)n * 8 + j] = make_float2(y0 - m - ls, y1 - m - ls);
    }
}

// ---------------- launch ----------------

extern "C" void kernel_launch(void* const* d_in, const int* in_sizes, int n_in,
                              void* d_out, int out_size, void* d_ws, size_t ws_size,
                              hipStream_t stream) {
    const float* x   = (const float*)d_in[0];
    const int*   ei  = (const int*)d_in[1];
    const float* W1  = (const float*)d_in[2];
    const float* a1s = (const float*)d_in[3];
    const float* a1d = (const float*)d_in[4];
    const float* b1  = (const float*)d_in[5];
    const float* W2  = (const float*)d_in[6];
    const float* a2s = (const float*)d_in[7];
    const float* a2d = (const float*)d_in[8];
    const float* b2  = (const float*)d_in[9];
    float* out = (float*)d_out;

    const int* srcA = ei;        // edge_index[0]
    const int* dstA = ei + NE;   // edge_index[1]

    char* w = (char*)d_ws;
    size_t off = 0;
    auto carve = [&](size_t bytes) -> void* {
        void* p = w + off;
        off = (off + bytes + 255) & ~(size_t)255;
        return p;
    };
    unsigned int* xw1b = (unsigned int*)carve((size_t)NN * 32); // 3.2 MB fp8 rows
    float* as1     = (float*)carve((size_t)NN * H1 * 4);      // 1.6 MB
    float* ad1     = (float*)carve((size_t)NN * H1 * 4);      // 1.6 MB
    // pairs (6.8MB) aliases h1h+xw2h (9.6MB): pairs dies at k_sort, h1h/xw2h
    // are written only by later kernels (stream-ordered) -> safe.
    size_t h1_off  = off;
    _Float16* h1h  = (_Float16*)carve((size_t)NN * F1 * 2);   // 6.4 MB
    _Float16* xw2h = (_Float16*)carve((size_t)NN * FOUT * 2); // 3.2 MB
    float* as2     = (float*)carve((size_t)NN * 4);
    float* ad2     = (float*)carve((size_t)NN * 4);
    int* pairs     = (int*)(w + h1_off);                      // alias
    int* rowstart  = (int*)carve((size_t)(NN + 1) * 4);
    int* epack     = (int*)carve((size_t)(ET + 64) * 4);      // 6.8 MB (+pad)
    int* ptotal    = (int*)carve((size_t)NPART * CPAD * 4);   // 25 KB
    int* gcur      = (int*)carve((size_t)NPART * CPAD * 4);   // 25 KB
    int* pbase     = (int*)carve((size_t)(NPART + 1) * 4);
    (void)ws_size; (void)in_sizes; (void)n_in; (void)out_size;

    hipMemsetAsync(ptotal, 0, (size_t)NPART * CPAD * 4, stream);

    k_hist  <<<NBLK, 1024, 0, stream>>>(dstA, ptotal);
    k_pbase <<<1, 512, 0, stream>>>(ptotal, pbase, gcur, rowstart);
    k_part  <<<NBLK, 1024, 0, stream>>>(srcA, dstA, gcur, pairs);
    k_sort  <<<NPART, 1024, 0, stream>>>(pbase, pairs, rowstart, epack);

    k_gemm1 <<<(NN + 255) / 256, 256, 0, stream>>>(x, W1, a1s, a1d, xw1b, as1, ad1);
    k_gather1<<<GBLK, 256, 0, stream>>>(rowstart, epack, as1, ad1, xw1b, b1, h1h);
    k_node2 <<<(NN + 255) / 256, 256, 0, stream>>>(h1h, W2, a2s, a2d, xw2h, as2, ad2);
    k_gather2<<<GBLK, 256, 0, stream>>>(rowstart, epack, as2, ad2, xw2h, b2, out);
}

// Round 5
// 238.809 us; speedup vs baseline: 1.0384x; 1.0288x over previous
//
#include <hip/hip_runtime.h>
#include <math.h>

// Problem constants (from setup_inputs)
#define NN 100000            // nodes
#define NE 1600000           // real edges
#define ET (NE + NN)         // edges + self loops = 1,700,000
#define FIN 128
#define H1 4
#define C1 8
#define F1 32                // H1*C1
#define FOUT 16
#define NSLOPE 0.2f

// Radix-partition parameters (CSR build)
#define PARTW 256                          // nodes per dst-partition
#define PSHIFT 8
#define NPART ((NN + PARTW - 1) / PARTW)   // 391
#define CHUNK 8192                         // edges per hist/part block
#define NBLK ((ET + CHUNK - 1) / CHUNK)    // 208
#define CPAD 16                            // ints: 1 global counter per 64B line
#define SMASK 0x1FFFF                      // low 17 bits = src id

typedef _Float16 half8 __attribute__((ext_vector_type(8)));
typedef _Float16 half4_t __attribute__((ext_vector_type(4)));
typedef _Float16 half2_t __attribute__((ext_vector_type(2)));
typedef float f32x4 __attribute__((ext_vector_type(4)));

// fp8 e4m3 (OCP on gfx950) decode: byte SEL of packed word -> f32.
template <int SEL>
__device__ inline float fp8dec(unsigned int w) {
    return __builtin_amdgcn_cvt_f32_fp8((int)w, SEL);
}

// ---------------- scan helpers ----------------

__device__ inline int wave_incl_scan(int v) {
#pragma unroll
    for (int off = 1; off < 64; off <<= 1) {
        int u = __shfl_up(v, off);
        if ((threadIdx.x & 63) >= off) v += u;
    }
    return v;
}

__device__ inline int block_excl_scan(int v, int* wsum, int nw) {
    int t = threadIdx.x, wid = t >> 6, lane = t & 63;
    int incl = wave_incl_scan(v);
    if (lane == 63) wsum[wid] = incl;
    __syncthreads();
    if (wid == 0) {
        int wv = (lane < nw) ? wsum[lane] : 0;
        wv = wave_incl_scan(wv);
        if (lane < nw) wsum[lane] = wv;
    }
    __syncthreads();
    return incl - v + (wid ? wsum[wid - 1] : 0);
}

// ---------------- CSR build (R10 versions) ----------------

__global__ __launch_bounds__(1024) void k_hist(const int* __restrict__ dstA, int* __restrict__ ptotal) {
    __shared__ int h[NPART];
    int t = threadIdx.x;
    for (int i = t; i < NPART; i += 1024) h[i] = 0;
    __syncthreads();
    int base = blockIdx.x * CHUNK;
#pragma unroll
    for (int k = 0; k < CHUNK / 1024; k++) {
        int e = base + k * 1024 + t;
        if (e < ET) {
            int d = (e < NE) ? dstA[e] : (e - NE);   // virtual self-loop edges
            atomicAdd(&h[d >> PSHIFT], 1);
        }
    }
    __syncthreads();
    for (int i = t; i < NPART; i += 1024)
        if (h[i]) atomicAdd(&ptotal[i * CPAD], h[i]);
}

__global__ __launch_bounds__(512) void k_pbase(const int* __restrict__ ptotal, int* __restrict__ pbase,
                                               int* __restrict__ gcur, int* __restrict__ rowstart) {
    __shared__ int wsum[8];
    int t = threadIdx.x;
    int v = (t < NPART) ? ptotal[t * CPAD] : 0;
    int excl = block_excl_scan(v, wsum, 8);
    if (t < NPART) { pbase[t] = excl; gcur[t * CPAD] = excl; }
    if (t == 0) { pbase[NPART] = ET; rowstart[NN] = ET; }
}

__global__ __launch_bounds__(1024) void k_part(const int* __restrict__ srcA, const int* __restrict__ dstA,
                                               int* __restrict__ gcur, int* __restrict__ pairs) {
    __shared__ int h[NPART];
    __shared__ int cur[NPART];
    int t = threadIdx.x;
    for (int i = t; i < NPART; i += 1024) h[i] = 0;
    __syncthreads();
    int base = blockIdx.x * CHUNK;
#pragma unroll
    for (int k = 0; k < CHUNK / 1024; k++) {
        int e = base + k * 1024 + t;
        if (e < ET) {
            int d = (e < NE) ? dstA[e] : (e - NE);
            atomicAdd(&h[d >> PSHIFT], 1);
        }
    }
    __syncthreads();
    for (int i = t; i < NPART; i += 1024) {
        int c = h[i];
        cur[i] = c ? atomicAdd(&gcur[i * CPAD], c) : 0;   // reserve contiguous range
    }
    __syncthreads();
#pragma unroll
    for (int k = 0; k < CHUNK / 1024; k++) {
        int e = base + k * 1024 + t;
        if (e < ET) {
            int s, d;
            if (e < NE) { s = srcA[e]; d = dstA[e]; }
            else        { s = e - NE;  d = s; }
            int pos = atomicAdd(&cur[d >> PSHIFT], 1);    // LDS atomic
            pairs[pos] = ((d & (PARTW - 1)) << 17) | s;   // src < 2^17, dloc < 2^8
        }
    }
}

__global__ __launch_bounds__(1024) void k_sort(const int* __restrict__ pbase, const int* __restrict__ pairs,
                                               int* __restrict__ rowstart, int* __restrict__ epack) {
    __shared__ int hist[PARTW];
    __shared__ int sa[PARTW], sb[PARTW];
    int p = blockIdx.x;
    int t = threadIdx.x;
    int n0 = p << PSHIFT;
    int nn = min(PARTW, NN - n0);
    int base = pbase[p];
    int cnt = pbase[p + 1] - base;
    if (t < PARTW) hist[t] = 0;
    __syncthreads();
    for (int i = t; i < cnt; i += 1024)
        atomicAdd(&hist[pairs[base + i] >> 17], 1);
    __syncthreads();
    if (t < PARTW) sa[t] = hist[t];
    __syncthreads();
    int* pin = sa; int* pout = sb;
    for (int off = 1; off < PARTW; off <<= 1) {
        if (t < PARTW) pout[t] = pin[t] + ((t >= off) ? pin[t - off] : 0);
        __syncthreads();
        int* tmp = pin; pin = pout; pout = tmp;
    }
    int excl = 0;
    if (t < PARTW) {
        excl = pin[t] - hist[t];
        if (t < nn) rowstart[n0 + t] = base + excl;
    }
    __syncthreads();
    if (t < PARTW) hist[t] = excl;   // reuse as cursor
    __syncthreads();
    for (int i = t; i < cnt; i += 1024) {
        int v = pairs[base + i];
        int pos = base + atomicAdd(&hist[v >> 17], 1);  // LDS atomic
        epack[pos] = v;
    }
}

// ---------------- Layer 1: x@W1 via MFMA ----------------
// Output row per node = 64B, ONE cache line holding everything gather1 needs:
//   words 0-7 : 32 channels as fp8 e4m3
//   words 8-11: as1[h] f32 (4 heads)
//   words 12-15: pad
// => exactly 1 random line-miss per edge in k_gather1 (was 2: as1 + xw tables).

__global__ __launch_bounds__(256) void k_gemm1(const float* __restrict__ x, const float* __restrict__ W1,
        const float* __restrict__ a1s, const float* __restrict__ a1d,
        unsigned int* __restrict__ xc1, float* __restrict__ ad1) {
    __shared__ _Float16 w1t[F1 * FIN];   // [n][k], 8 KB
    __shared__ float xs[256 * F1];       // [node_loc][col], 32 KB
    int t = threadIdx.x;
    {
        int i0 = t * 16;
#pragma unroll
        for (int i = 0; i < 16; i++) {
            int idx = i0 + i;
            int k = idx >> 5, n = idx & 31;
            w1t[n * FIN + k] = (_Float16)W1[idx];
        }
    }
    __syncthreads();
    int w = t >> 6, l = t & 63;
    int q = l >> 4, r16 = l & 15;
    int nblk = blockIdx.x * 256;
    int n0 = nblk + w * 64;
    half8 bf[4][2];
#pragma unroll
    for (int kc = 0; kc < 4; kc++)
#pragma unroll
        for (int nt = 0; nt < 2; nt++)
            bf[kc][nt] = *(const half8*)&w1t[(nt * 16 + r16) * FIN + kc * 32 + q * 8];
#pragma unroll
    for (int mt = 0; mt < 4; mt++) {
        int row = n0 + mt * 16 + r16;
        int rowc = min(row, NN - 1);            // clamp: values discarded for OOB rows
        const float4* xp = (const float4*)(x + (size_t)rowc * FIN + q * 8);
        half8 af[4];
#pragma unroll
        for (int kc = 0; kc < 4; kc++) {
            float4 u = xp[kc * 8];
            float4 v = xp[kc * 8 + 1];
            half8 a;
            a[0] = (_Float16)u.x; a[1] = (_Float16)u.y; a[2] = (_Float16)u.z; a[3] = (_Float16)u.w;
            a[4] = (_Float16)v.x; a[5] = (_Float16)v.y; a[6] = (_Float16)v.z; a[7] = (_Float16)v.w;
            af[kc] = a;
        }
        f32x4 acc0 = {0.f, 0.f, 0.f, 0.f};
        f32x4 acc1 = {0.f, 0.f, 0.f, 0.f};
#pragma unroll
        for (int kc = 0; kc < 4; kc++) {
            acc0 = __builtin_amdgcn_mfma_f32_16x16x32_f16(af[kc], bf[kc][0], acc0, 0, 0, 0);
            acc1 = __builtin_amdgcn_mfma_f32_16x16x32_f16(af[kc], bf[kc][1], acc1, 0, 0, 0);
        }
#pragma unroll
        for (int r = 0; r < 4; r++) {
            xs[(w * 64 + mt * 16 + q * 4 + r) * F1 + r16] = acc0[r];
            xs[(w * 64 + mt * 16 + q * 4 + r) * F1 + 16 + r16] = acc1[r];
        }
    }
    int node = nblk + w * 64 + l;
    if (node < NN) {
        const float4* xr = (const float4*)&xs[(w * 64 + l) * F1];
        float rowv[F1];
#pragma unroll
        for (int j = 0; j < 8; j++) {
            float4 v = xr[j];
            rowv[j * 4] = v.x; rowv[j * 4 + 1] = v.y; rowv[j * 4 + 2] = v.z; rowv[j * 4 + 3] = v.w;
        }
        // pack 32 channels -> words 0..7 (fp8 e4m3)
        uint4 o[3];
        unsigned int* ow = (unsigned int*)o;
#pragma unroll
        for (int c4 = 0; c4 < 8; c4++) {
            int p = 0;
            p = __builtin_amdgcn_cvt_pk_fp8_f32(rowv[c4 * 4 + 0], rowv[c4 * 4 + 1], p, false);
            p = __builtin_amdgcn_cvt_pk_fp8_f32(rowv[c4 * 4 + 2], rowv[c4 * 4 + 3], p, true);
            ow[c4] = (unsigned int)p;
        }
        float ss[H1], dd[H1];
#pragma unroll
        for (int h = 0; h < H1; h++) {
            ss[h] = 0.f; dd[h] = 0.f;
#pragma unroll
            for (int c = 0; c < C1; c++) {
                ss[h] = fmaf(rowv[h * C1 + c], a1s[h * C1 + c], ss[h]);
                dd[h] = fmaf(rowv[h * C1 + c], a1d[h * C1 + c], dd[h]);
            }
        }
        // words 8..11: as1 per head
#pragma unroll
        for (int h = 0; h < H1; h++) ow[8 + h] = __float_as_uint(ss[h]);
        uint4* o16 = (uint4*)(xc1 + (size_t)node * 16);
        o16[0] = o[0];
        o16[1] = o[1];
        o16[2] = o[2];
        ((float4*)ad1)[node] = make_float4(dd[0], dd[1], dd[2], dd[3]);
    }
}

// ---------------- Layer 1 gather: single-line rows, 3-stage pipeline ----------------
// 1 wave/node (R3 structure — best measured). 8 edge-groups x 8 lanes; lane j
// owns channels {4j..4j+3} via one u32 (4 fp8) load from the combined row; the
// as1 coefficient (word 8+h) comes from the SAME 64B line -> 1 miss per edge.

__global__ __launch_bounds__(256) void k_gather1(const int* __restrict__ rowstart, const int* __restrict__ epack,
        const float* __restrict__ ad1, const unsigned int* __restrict__ xc1,
        const float* __restrict__ b1, _Float16* __restrict__ h1h) {
    int n = blockIdx.x * 4 + (threadIdx.x >> 6);
    if (n >= NN) return;
    int l = threadIdx.x & 63;
    int g = l >> 3;          // edge group 0..7
    int j = l & 7;           // channel-quad id 0..7
    int h = j >> 1;          // head 0..3
    float adh = ad1[n * H1 + h];
    int beg = rowstart[n], end = rowstart[n + 1];
    int endm1 = end - 1;
    float a0 = 0.f, a1 = 0.f, a2 = 0.f, a3 = 0.f, ad = 0.f;
    int i = beg + g;
    // stage 0+1: current pair (f/v ready), next pair's src ids
    int i0 = min(i, endm1), i1 = min(i + 8, endm1);
    int c0 = epack[i0] & SMASK, c1 = epack[i1] & SMASK;
    int i2 = min(i + 16, endm1), i3 = min(i + 24, endm1);
    int sn0 = epack[i2] & SMASK, sn1 = epack[i3] & SMASK;
    float f0 = __uint_as_float(xc1[c0 * 16 + 8 + h]);
    float f1 = __uint_as_float(xc1[c1 * 16 + 8 + h]);
    unsigned int v0 = xc1[c0 * 16 + j], v1 = xc1[c1 * 16 + j];
    while (i + 8 < end) {
        // issue dependent loads for i+16 (ids already resident); both dwords of
        // each edge hit the same 64B line (second is an MSHR merge, not a miss)
        float nf0 = __uint_as_float(xc1[sn0 * 16 + 8 + h]);
        float nf1 = __uint_as_float(xc1[sn1 * 16 + 8 + h]);
        unsigned int nv0 = xc1[sn0 * 16 + j], nv1 = xc1[sn1 * 16 + j];
        // issue epack loads for i+32
        int p0 = min(i + 32, endm1), p1 = min(i + 40, endm1);
        int u0 = epack[p0] & SMASK, u1 = epack[p1] & SMASK;
        // consume current pair
        float e0 = f0 + adh, e1 = f1 + adh;
        e0 = (e0 > 0.f) ? e0 : NSLOPE * e0;
        e1 = (e1 > 0.f) ? e1 : NSLOPE * e1;
        float w0 = __expf(e0), w1 = __expf(e1);
        ad += w0 + w1;
        a0 = fmaf(w0, fp8dec<0>(v0), fmaf(w1, fp8dec<0>(v1), a0));
        a1 = fmaf(w0, fp8dec<1>(v0), fmaf(w1, fp8dec<1>(v1), a1));
        a2 = fmaf(w0, fp8dec<2>(v0), fmaf(w1, fp8dec<2>(v1), a2));
        a3 = fmaf(w0, fp8dec<3>(v0), fmaf(w1, fp8dec<3>(v1), a3));
        f0 = nf0; f1 = nf1; v0 = nv0; v1 = nv1;
        sn0 = u0; sn1 = u1;
        i += 16;
    }
    if (i < end) {           // at most one leftover edge per lane (i+8 >= end)
        float e0 = f0 + adh;
        e0 = (e0 > 0.f) ? e0 : NSLOPE * e0;
        float w0 = __expf(e0);
        ad += w0;
        a0 = fmaf(w0, fp8dec<0>(v0), a0);
        a1 = fmaf(w0, fp8dec<1>(v0), a1);
        a2 = fmaf(w0, fp8dec<2>(v0), a2);
        a3 = fmaf(w0, fp8dec<3>(v0), a3);
    }
#pragma unroll
    for (int off = 8; off < 64; off <<= 1) {
        a0 += __shfl_xor(a0, off);
        a1 += __shfl_xor(a1, off);
        a2 += __shfl_xor(a2, off);
        a3 += __shfl_xor(a3, off);
        ad += __shfl_xor(ad, off);
    }
    if (l < 8) {
        float inv = 1.0f / ad;
        float y0 = fmaf(a0, inv, b1[4 * j]);
        float y1 = fmaf(a1, inv, b1[4 * j + 1]);
        float y2 = fmaf(a2, inv, b1[4 * j + 2]);
        float y3 = fmaf(a3, inv, b1[4 * j + 3]);
        y0 = (y0 > 0.f) ? y0 : expm1f(y0);   // ELU
        y1 = (y1 > 0.f) ? y1 : expm1f(y1);
        y2 = (y2 > 0.f) ? y2 : expm1f(y2);
        y3 = (y3 > 0.f) ? y3 : expm1f(y3);
        half4_t o;
        o[0] = (_Float16)y0; o[1] = (_Float16)y1; o[2] = (_Float16)y2; o[3] = (_Float16)y3;
        ((half4_t*)h1h)[(size_t)n * 8 + j] = o;
    }
}

// ---------------- Layer 2 node transform: h1@W2 + attention coefficients ----------------
// Combined row per node = 64B: words 0-7 = 16 fp16 channels, word 8 = as2 f32,
// rest pad. One line per edge in k_gather2.

__global__ __launch_bounds__(256) void k_node2(const _Float16* __restrict__ h1h, const float* __restrict__ W2,
        const float* __restrict__ a2s, const float* __restrict__ a2d,
        unsigned int* __restrict__ xc2, float* __restrict__ ad2) {
    int n = blockIdx.x * 256 + threadIdx.x;
    if (n >= NN) return;
    float acc[FOUT];
#pragma unroll
    for (int j = 0; j < FOUT; j++) acc[j] = 0.f;
    const half8* h8 = (const half8*)(h1h + (size_t)n * F1);
#pragma unroll
    for (int i8 = 0; i8 < F1 / 8; i8++) {
        half8 hv = h8[i8];
#pragma unroll
        for (int kk = 0; kk < 8; kk++) {
            float hk = (float)hv[kk];
            int i = i8 * 8 + kk;
#pragma unroll
            for (int j = 0; j < FOUT; j++)
                acc[j] = fmaf(hk, W2[i * FOUT + j], acc[j]);   // wave-uniform -> scalar
        }
    }
    float ss = 0.f, dd = 0.f;
#pragma unroll
    for (int j = 0; j < FOUT; j++) {
        ss = fmaf(acc[j], a2s[j], ss);
        dd = fmaf(acc[j], a2d[j], dd);
    }
    uint4 o[2];
    unsigned int* ow = (unsigned int*)o;
#pragma unroll
    for (int p = 0; p < 8; p++) {
        half2_t hp;
        hp[0] = (_Float16)acc[2 * p];
        hp[1] = (_Float16)acc[2 * p + 1];
        ow[p] = *(unsigned int*)&hp;
    }
    uint4* o16 = (uint4*)(xc2 + (size_t)n * 16);
    o16[0] = o[0];
    o16[1] = o[1];
    xc2[(size_t)n * 16 + 8] = __float_as_uint(ss);
    ad2[n] = dd;
}

// ---------------- Layer 2 gather: single-line rows + log_softmax ----------------
// 1 wave/node. 8 edge-groups x 8 lanes; lane j owns channels {2j,2j+1} via one
// half2 load; as2 (word 8) from the SAME line -> 1 miss per edge.

__global__ __launch_bounds__(256) void k_gather2(const int* __restrict__ rowstart, const int* __restrict__ epack,
        const float* __restrict__ ad2, const unsigned int* __restrict__ xc2,
        const float* __restrict__ b2, float* __restrict__ out) {
    int n = blockIdx.x * 4 + (threadIdx.x >> 6);
    if (n >= NN) return;
    int l = threadIdx.x & 63;
    int g = l >> 3;          // edge group 0..7
    int j = l & 7;           // channel-pair id 0..7
    float adn = ad2[n];
    const half2_t* xw = (const half2_t*)xc2;   // u32 word k == half2 slot k
    int beg = rowstart[n], end = rowstart[n + 1];
    int endm1 = end - 1;
    float a0 = 0.f, a1v = 0.f, ad = 0.f;
    int i = beg + g;
    int i0 = min(i, endm1), i1 = min(i + 8, endm1);
    int c0 = epack[i0] & SMASK, c1 = epack[i1] & SMASK;
    int i2 = min(i + 16, endm1), i3 = min(i + 24, endm1);
    int sn0 = epack[i2] & SMASK, sn1 = epack[i3] & SMASK;
    float f0 = __uint_as_float(xc2[c0 * 16 + 8]);
    float f1 = __uint_as_float(xc2[c1 * 16 + 8]);
    half2_t v0 = xw[c0 * 16 + j], v1 = xw[c1 * 16 + j];
    while (i + 8 < end) {
        float nf0 = __uint_as_float(xc2[sn0 * 16 + 8]);
        float nf1 = __uint_as_float(xc2[sn1 * 16 + 8]);
        half2_t nv0 = xw[sn0 * 16 + j], nv1 = xw[sn1 * 16 + j];
        int p0 = min(i + 32, endm1), p1 = min(i + 40, endm1);
        int u0 = epack[p0] & SMASK, u1 = epack[p1] & SMASK;
        float e0 = f0 + adn, e1 = f1 + adn;
        e0 = (e0 > 0.f) ? e0 : NSLOPE * e0;
        e1 = (e1 > 0.f) ? e1 : NSLOPE * e1;
        float w0 = __expf(e0), w1 = __expf(e1);
        ad += w0 + w1;
        a0  = fmaf(w0, (float)v0[0], fmaf(w1, (float)v1[0], a0));
        a1v = fmaf(w0, (float)v0[1], fmaf(w1, (float)v1[1], a1v));
        f0 = nf0; f1 = nf1; v0 = nv0; v1 = nv1;
        sn0 = u0; sn1 = u1;
        i += 16;
    }
    if (i < end) {
        float e0 = f0 + adn;
        e0 = (e0 > 0.f) ? e0 : NSLOPE * e0;
        float w0 = __expf(e0);
        ad += w0;
        a0  = fmaf(w0, (float)v0[0], a0);
        a1v = fmaf(w0, (float)v0[1], a1v);
    }
#pragma unroll
    for (int off = 8; off < 64; off <<= 1) {
        a0  += __shfl_xor(a0, off);
        a1v += __shfl_xor(a1v, off);
        ad  += __shfl_xor(ad, off);
    }
    float inv = 1.0f / ad;
    float y0 = fmaf(a0, inv, b2[2 * j]);
    float y1 = fmaf(a1v, inv, b2[2 * j + 1]);
    // log_softmax over 16 channels (8 lanes x 2 regs)
    float m = fmaxf(y0, y1);
#pragma unroll
    for (int off = 1; off < 8; off <<= 1) m = fmaxf(m, __shfl_xor(m, off));
    float s = __expf(y0 - m) + __expf(y1 - m);
#pragma unroll
    for (int off = 1; off < 8; off <<= 1) s += __shfl_xor(s, off);
    float ls = logf(s);
    if (l < 8)
        ((float2*)out)[(size_t)n * 8 + j] = make_float2(y0 - m - ls, y1 - m - ls);
}

// ---------------- launch ----------------

extern "C" void kernel_launch(void* const* d_in, const int* in_sizes, int n_in,
                              void* d_out, int out_size, void* d_ws, size_t ws_size,
                              hipStream_t stream) {
    const float* x   = (const float*)d_in[0];
    const int*   ei  = (const int*)d_in[1];
    const float* W1  = (const float*)d_in[2];
    const float* a1s = (const float*)d_in[3];
    const float* a1d = (const float*)d_in[4];
    const float* b1  = (const float*)d_in[5];
    const float* W2  = (const float*)d_in[6];
    const float* a2s = (const float*)d_in[7];
    const float* a2d = (const float*)d_in[8];
    const float* b2  = (const float*)d_in[9];
    float* out = (float*)d_out;

    const int* srcA = ei;        // edge_index[0]
    const int* dstA = ei + NE;   // edge_index[1]

    char* w = (char*)d_ws;
    size_t off = 0;
    auto carve = [&](size_t bytes) -> void* {
        void* p = w + off;
        off = (off + bytes + 255) & ~(size_t)255;
        return p;
    };
    // pairs (6.8MB) aliases xc1+ad1 (8MB): pairs dies at k_sort; xc1/ad1 are
    // written only by k_gemm1 which runs after k_sort (stream-ordered) -> safe.
    size_t xc1_off = off;
    unsigned int* xc1 = (unsigned int*)carve((size_t)NN * 64);  // 6.4 MB combined L1 rows
    float* ad1     = (float*)carve((size_t)NN * H1 * 4);        // 1.6 MB
    _Float16* h1h  = (_Float16*)carve((size_t)NN * F1 * 2);     // 6.4 MB
    unsigned int* xc2 = (unsigned int*)carve((size_t)NN * 64);  // 6.4 MB combined L2 rows
    float* ad2     = (float*)carve((size_t)NN * 4);
    int* pairs     = (int*)(w + xc1_off);                       // alias
    int* rowstart  = (int*)carve((size_t)(NN + 1) * 4);
    int* epack     = (int*)carve((size_t)(ET + 64) * 4);        // 6.8 MB (+pad)
    int* ptotal    = (int*)carve((size_t)NPART * CPAD * 4);     // 25 KB
    int* gcur      = (int*)carve((size_t)NPART * CPAD * 4);     // 25 KB
    int* pbase     = (int*)carve((size_t)(NPART + 1) * 4);
    (void)ws_size; (void)in_sizes; (void)n_in; (void)out_size;

    hipMemsetAsync(ptotal, 0, (size_t)NPART * CPAD * 4, stream);

    k_hist  <<<NBLK, 1024, 0, stream>>>(dstA, ptotal);
    k_pbase <<<1, 512, 0, stream>>>(ptotal, pbase, gcur, rowstart);
    k_part  <<<NBLK, 1024, 0, stream>>>(srcA, dstA, gcur, pairs);
    k_sort  <<<NPART, 1024, 0, stream>>>(pbase, pairs, rowstart, epack);

    k_gemm1 <<<(NN + 255) / 256, 256, 0, stream>>>(x, W1, a1s, a1d, xc1, ad1);
    k_gather1<<<(NN + 3) / 4, 256, 0, stream>>>(rowstart, epack, ad1, xc1, b1, h1h);
    k_node2 <<<(NN + 255) / 256, 256, 0, stream>>>(h1h, W2, a2s, a2d, xc2, ad2);
    k_gather2<<<(NN + 3) / 4, 256, 0, stream>>>(rowstart, epack, ad2, xc2, b2, out);
}